// Round 10
// baseline (338.001 us; speedup 1.0000x reference)
//
#include <hip/hip_runtime.h>
#include <cstdint>
#include <cstddef>

// GCN on MI355X, round 10: bucketed CSR (transposed keys) + REGISTER-acc aggs.
//   out[50000,64] = log_softmax(gcn2(relu(gcn1(x))))
// Keys: bucket(src)*n + dst, bucket(s)=(s>>11)&3 (4 stripes x ~3.2MB table).
// Agg kernels: bucket-outer / unrolled-rows-inner, acc in registers (RPW=8),
// no LDS, fixed rows/wave. Grid-wide gathers focus one stripe at a time.

#define N_FEAT 128
#define RPW 8         // rows per wave in agg kernels (compile-time, unrolled)

typedef short bf16x8 __attribute__((ext_vector_type(8)));
typedef float f32x4 __attribute__((ext_vector_type(4)));

__device__ __forceinline__ unsigned f2bf(float f) {
  unsigned u = __float_as_uint(f);
  return (u + 0x7FFFu + ((u >> 16) & 1u)) >> 16;   // round-to-nearest-even
}
__device__ __forceinline__ float bflo(unsigned u) { return __uint_as_float(u << 16); }
__device__ __forceinline__ float bfhi(unsigned u) { return __uint_as_float(u & 0xFFFF0000u); }
__device__ __forceinline__ int bkt(int s) { return (s >> 11) & 3; }

// ---------------- preprocessing ----------------

// Histogram over keys (bucket(src)*n + dst) + per-edge within-key rank.
__global__ void k_hist(const int* __restrict__ src, const int* __restrict__ dst,
                       int* __restrict__ cnt2, int* __restrict__ rank, int E, int n) {
  int e = blockIdx.x * blockDim.x + threadIdx.x;
  if (e >= E) return;
  int key = bkt(src[e]) * n + dst[e];
  rank[e] = atomicAdd(&cnt2[key], 1);
}

// Per-block sums of padded key counts; also dinv per row (64 rows/block).
__global__ __launch_bounds__(256) void k_bsum(const int* __restrict__ cnt2,
                                              int* __restrict__ bsum,
                                              float* __restrict__ dinv,
                                              int m, int n) {
  int i = blockIdx.x * 256 + threadIdx.x;
  int v = (i < m) ? ((cnt2[i] + 3) & ~3) : 0;
  for (int o = 32; o > 0; o >>= 1) v += __shfl_down(v, o);
  __shared__ int w[4];
  if ((threadIdx.x & 63) == 0) w[threadIdx.x >> 6] = v;
  __syncthreads();
  if (threadIdx.x == 0) bsum[blockIdx.x] = w[0] + w[1] + w[2] + w[3];
  int row = blockIdx.x * 64 + threadIdx.x;   // first 64 threads: dinv
  if (threadIdx.x < 64 && row < n) {
    int deg = cnt2[row] + cnt2[n + row] + cnt2[2 * n + row] + cnt2[3 * n + row];
    dinv[row] = rsqrtf((float)(deg + 1));    // +1 self-loop
  }
}

__global__ __launch_bounds__(1024) void k_bscan(const int* __restrict__ bsum,
                                                int* __restrict__ bbase, int nb) {
  __shared__ int lds[1024];
  int t = threadIdx.x;
  int v = (t < nb) ? bsum[t] : 0;
  lds[t] = v;
  __syncthreads();
  for (int o = 1; o < 1024; o <<= 1) {
    int u = (t >= o) ? lds[t - o] : 0;
    __syncthreads();
    lds[t] += u;
    __syncthreads();
  }
  if (t < nb) bbase[t] = lds[t] - v;   // exclusive
}

// Local scan over padded key counts -> rp2; zero dummy pad slots.
__global__ __launch_bounds__(256) void k_scan2(const int* __restrict__ cnt2,
                                               const int* __restrict__ bbase,
                                               int* __restrict__ rp2,
                                               unsigned* __restrict__ desc, int m) {
  __shared__ int lds[256];
  int t = threadIdx.x;
  int i = blockIdx.x * 256 + t;
  int c  = (i < m) ? cnt2[i] : 0;
  int pc = (c + 3) & ~3;
  lds[t] = pc;
  __syncthreads();
  for (int o = 1; o < 256; o <<= 1) {
    int u = (t >= o) ? lds[t - o] : 0;
    __syncthreads();
    lds[t] += u;
    __syncthreads();
  }
  if (i < m) {
    int excl = bbase[blockIdx.x] + lds[t] - pc;
    rp2[i] = excl;
    for (int p = excl + c; p < excl + pc; ++p) desc[p] = 0;  // dummy edges
    if (i == m - 1) rp2[m] = excl + pc;
  }
}

__global__ void k_fill(const int* __restrict__ src, const int* __restrict__ dst,
                       const int* __restrict__ rank, const int* __restrict__ rp2,
                       const float* __restrict__ dinv,
                       unsigned* __restrict__ desc, int E, int n) {
  int e = blockIdx.x * blockDim.x + threadIdx.x;
  if (e >= E) return;
  int s = src[e], d = dst[e];
  int p = rp2[bkt(s) * n + d] + rank[e];
  desc[p] = (f2bf(dinv[s] * dinv[d]) << 16) | (unsigned)s;
}

// ---------------- MFMA GEMMs (round-6, unchanged) ----------------

template<int NCOL, bool XF32>
__global__ __launch_bounds__(256) void k_gemm_mfma(const void* __restrict__ Xv,
                                                   const float* __restrict__ W,
                                                   unsigned short* __restrict__ Yb,
                                                   int n) {
  constexpr int NT = NCOL / 16;
  __shared__ uint4 Xl[64][16];
  __shared__ uint4 Wl[NCOL][16];
  int t = threadIdx.x;
  int row0 = blockIdx.x * 64;

  for (int c = t; c < 1024; c += 256) {
    int lr = c >> 4, kc = c & 15;
    int row = row0 + lr;
    uint4 v = {0u, 0u, 0u, 0u};
    if (row < n) {
      if constexpr (XF32) {
        const float* Xf = (const float*)Xv;
        float4 f0 = *(const float4*)(Xf + (size_t)row * 128 + kc * 8);
        float4 f1 = *(const float4*)(Xf + (size_t)row * 128 + kc * 8 + 4);
        v.x = f2bf(f0.x) | (f2bf(f0.y) << 16);
        v.y = f2bf(f0.z) | (f2bf(f0.w) << 16);
        v.z = f2bf(f1.x) | (f2bf(f1.y) << 16);
        v.w = f2bf(f1.z) | (f2bf(f1.w) << 16);
      } else {
        v = ((const uint4*)Xv)[(size_t)row * 16 + kc];
      }
    }
    Xl[lr][kc ^ (lr & 7)] = v;
  }
  {
    int j = t % NCOL, kc0 = t / NCOL;
    for (int kc = kc0; kc < 16; kc += 256 / NCOL) {
      const float* wp = W + (size_t)(kc * 8) * NCOL + j;
      float f[8];
#pragma unroll
      for (int e = 0; e < 8; ++e) f[e] = wp[e * NCOL];
      uint4 v;
      v.x = f2bf(f[0]) | (f2bf(f[1]) << 16);
      v.y = f2bf(f[2]) | (f2bf(f[3]) << 16);
      v.z = f2bf(f[4]) | (f2bf(f[5]) << 16);
      v.w = f2bf(f[6]) | (f2bf(f[7]) << 16);
      Wl[j][kc ^ (j & 7)] = v;
    }
  }
  __syncthreads();

  int w = t >> 6, lane = t & 63;
  int lr16 = lane & 15, kg = lane >> 4;
  bf16x8 a[4];
#pragma unroll
  for (int kk = 0; kk < 4; ++kk)
    a[kk] = __builtin_bit_cast(bf16x8, Xl[w * 16 + lr16][(kk * 4 + kg) ^ (lane & 7)]);
#pragma unroll
  for (int jt = 0; jt < NT; ++jt) {
    f32x4 acc = {0.0f, 0.0f, 0.0f, 0.0f};
#pragma unroll
    for (int kk = 0; kk < 4; ++kk) {
      bf16x8 bb = __builtin_bit_cast(bf16x8, Wl[jt * 16 + lr16][(kk * 4 + kg) ^ (lane & 7)]);
      acc = __builtin_amdgcn_mfma_f32_16x16x32_bf16(a[kk], bb, acc, 0, 0, 0);
    }
    int col = jt * 16 + lr16;
#pragma unroll
    for (int r = 0; r < 4; ++r) {
      int row = row0 + w * 16 + kg * 4 + r;
      if (row < n) Yb[(size_t)row * NCOL + col] = (unsigned short)f2bf(acc[r]);
    }
  }
}

// ---------------- aggregations (bucket-outer, register acc) ----------------

// Layer-1: wave owns rows [wv*RPW, wv*RPW+RPW). Lane owns cols {2l,2l+1}.
// acc in registers (statically indexed via full unroll); 4 edges/iter.
__global__ __launch_bounds__(256) void k_agg128R(const unsigned* __restrict__ desc,
                                                 const int* __restrict__ rp2,
                                                 const float* __restrict__ dinv,
                                                 const float* __restrict__ bias,
                                                 const unsigned* __restrict__ xwb,
                                                 unsigned* __restrict__ hb, int n) {
  int wv   = (blockIdx.x * 256 + threadIdx.x) >> 6;
  int lane = threadIdx.x & 63;
  int gr0  = wv * RPW;
  if (gr0 >= n) return;
  float b0 = bias[2 * lane], b1 = bias[2 * lane + 1];
  float accx[RPW], accy[RPW];
#pragma unroll
  for (int r = 0; r < RPW; ++r) {
    accx[r] = 0.0f; accy[r] = 0.0f;
    int gr = gr0 + r;
    if (gr < n) {
      float di = dinv[gr];
      float sl = di * di;
      unsigned us = xwb[(size_t)gr * 64 + lane];
      accx[r] = b0 + bflo(us) * sl;
      accy[r] = b1 + bfhi(us) * sl;
    }
  }
#pragma unroll
  for (int b = 0; b < 4; ++b) {
    const int* rp = rp2 + b * n + gr0;
#pragma unroll
    for (int r = 0; r < RPW; ++r) {
      int gr = gr0 + r;
      if (gr < n) {
        int beg = rp[r], end = rp[r + 1];
        float ax = 0.0f, ay = 0.0f, bx = 0.0f, by = 0.0f;
        for (int base = beg; base < end; base += 4) {
          uint4 d4 = *(const uint4*)(desc + base);
          unsigned u0 = xwb[(size_t)(d4.x & 0xFFFFu) * 64 + lane];
          unsigned u1 = xwb[(size_t)(d4.y & 0xFFFFu) * 64 + lane];
          unsigned u2 = xwb[(size_t)(d4.z & 0xFFFFu) * 64 + lane];
          unsigned u3 = xwb[(size_t)(d4.w & 0xFFFFu) * 64 + lane];
          float n0 = bfhi(d4.x), n1 = bfhi(d4.y), n2 = bfhi(d4.z), n3 = bfhi(d4.w);
          ax += bflo(u0) * n0; ay += bfhi(u0) * n0;
          bx += bflo(u1) * n1; by += bfhi(u1) * n1;
          ax += bflo(u2) * n2; ay += bfhi(u2) * n2;
          bx += bflo(u3) * n3; by += bfhi(u3) * n3;
        }
        accx[r] += ax + bx;
        accy[r] += ay + by;
      }
    }
  }
#pragma unroll
  for (int r = 0; r < RPW; ++r) {
    int gr = gr0 + r;
    if (gr < n)
      hb[(size_t)gr * 64 + lane] =
          f2bf(fmaxf(accx[r], 0.0f)) | (f2bf(fmaxf(accy[r], 0.0f)) << 16);
  }
}

// Layer-2 + log_softmax: half-wave per edge-pair; lane owns cols {2c,2c+1}.
__global__ __launch_bounds__(256) void k_agg64R(const unsigned* __restrict__ desc,
                                                const int* __restrict__ rp2,
                                                const float* __restrict__ dinv,
                                                const float* __restrict__ bias,
                                                const unsigned* __restrict__ hwb,
                                                float* __restrict__ out, int n) {
  int wv   = (blockIdx.x * 256 + threadIdx.x) >> 6;
  int lane = threadIdx.x & 63;
  int gr0  = wv * RPW;
  if (gr0 >= n) return;
  int c    = lane & 31;
  int half = lane >> 5;
  float bc0 = bias[2 * c], bc1 = bias[2 * c + 1];
  float accx[RPW], accy[RPW];
#pragma unroll
  for (int r = 0; r < RPW; ++r) {
    accx[r] = 0.0f; accy[r] = 0.0f;
    int gr = gr0 + r;
    if (half == 0 && gr < n) {   // self-loop + bias counted once
      float di = dinv[gr];
      unsigned us = hwb[(size_t)gr * 32 + c];
      accx[r] = bc0 + bflo(us) * di * di;
      accy[r] = bc1 + bfhi(us) * di * di;
    }
  }
#pragma unroll
  for (int b = 0; b < 4; ++b) {
    const int* rp = rp2 + b * n + gr0;
#pragma unroll
    for (int r = 0; r < RPW; ++r) {
      int gr = gr0 + r;
      if (gr < n) {
        int beg = rp[r], end = rp[r + 1];
        float ax = 0.0f, ay = 0.0f, bx = 0.0f, by = 0.0f;
        for (int base = beg; base < end; base += 4) {
          uint4 d4 = *(const uint4*)(desc + base);
          unsigned dA = half ? d4.z : d4.x;
          unsigned dB = half ? d4.w : d4.y;
          unsigned uA = hwb[(size_t)(dA & 0xFFFFu) * 32 + c];
          unsigned uB = hwb[(size_t)(dB & 0xFFFFu) * 32 + c];
          float nA = bfhi(dA), nB = bfhi(dB);
          ax += bflo(uA) * nA; ay += bfhi(uA) * nA;
          bx += bflo(uB) * nB; by += bfhi(uB) * nB;
        }
        accx[r] += ax + bx;
        accy[r] += ay + by;
      }
    }
  }
#pragma unroll
  for (int r = 0; r < RPW; ++r) {
    int gr = gr0 + r;
    if (gr < n) {
      float vx = accx[r], vy = accy[r];
      vx += __shfl_xor(vx, 32);          // cross-half sum
      vy += __shfl_xor(vy, 32);
      float m = fmaxf(vx, vy);
      for (int o = 16; o > 0; o >>= 1) m = fmaxf(m, __shfl_xor(m, o));
      float s = expf(vx - m) + expf(vy - m);
      for (int o = 16; o > 0; o >>= 1) s += __shfl_xor(s, o);
      float ls = logf(s);
      if (half == 0) {
        float2 o2 = { vx - m - ls, vy - m - ls };
        *(float2*)(out + (size_t)gr * 64 + 2 * c) = o2;
      }
    }
  }
}

extern "C" void kernel_launch(void* const* d_in, const int* in_sizes, int n_in,
                              void* d_out, int out_size, void* d_ws, size_t ws_size,
                              hipStream_t stream) {
  const float* x  = (const float*)d_in[0];
  const int*   ei = (const int*)d_in[1];
  const float* W1 = (const float*)d_in[2];
  const float* b1 = (const float*)d_in[3];
  const float* W2 = (const float*)d_in[4];
  const float* b2 = (const float*)d_in[5];
  float* out = (float*)d_out;

  const int n = in_sizes[0] / N_FEAT;   // 50000
  const int E = in_sizes[1] / 2;        // 800000
  const int* src = ei;
  const int* dst = ei + E;
  const int m   = 4 * n;                // (bucket, dst) key space
  const int nb2 = (m + 255) / 256;      // 782 scan blocks (<=1024)
  const int nwv = (n + RPW - 1) / RPW;  // 6250 agg waves
  const int nbA = (nwv + 3) / 4;        // agg blocks

  auto align = [](size_t v) { return (v + 255) & ~(size_t)255; };
  char* ws = (char*)d_ws;
  size_t off = 0;
  int*      cnt2 = (int*)     (ws + off); off += align((size_t)m * 4);
  int*      rp2  = (int*)     (ws + off); off += align((size_t)(m + 1) * 4);
  float*    dinv = (float*)   (ws + off); off += align((size_t)n * 4);
  int*      rank = (int*)     (ws + off); off += align((size_t)E * 4);
  int*      bsum = (int*)     (ws + off); off += align(1024 * 4);
  int*      bbase= (int*)     (ws + off); off += align(1024 * 4);
  unsigned* desc = (unsigned*)(ws + off); off += align((size_t)(E + 3 * m + 64) * 4);
  unsigned* xwb  = (unsigned*)(ws + off); off += align((size_t)n * 64 * 4);  // bf16[n,128]
  unsigned* hb   = (unsigned*)(ws + off); off += align((size_t)n * 64 * 4);  // bf16[n,128]
  unsigned* hwb  = xwb;  // bf16[n,64] overlays xwb (dead after agg128)

  hipMemsetAsync(cnt2, 0, (size_t)m * 4, stream);
  k_hist<<<(E + 255) / 256, 256, 0, stream>>>(src, dst, cnt2, rank, E, n);
  k_bsum<<<nb2, 256, 0, stream>>>(cnt2, bsum, dinv, m, n);
  k_bscan<<<1, 1024, 0, stream>>>(bsum, bbase, nb2);
  k_scan2<<<nb2, 256, 0, stream>>>(cnt2, bbase, rp2, desc, m);
  k_fill<<<(E + 255) / 256, 256, 0, stream>>>(src, dst, rank, rp2, dinv, desc, E, n);

  // Layer 1
  k_gemm_mfma<128, true><<<(n + 63) / 64, 256, 0, stream>>>(
      x, W1, (unsigned short*)xwb, n);
  k_agg128R<<<nbA, 256, 0, stream>>>(desc, rp2, dinv, b1, xwb, hb, n);

  // Layer 2
  k_gemm_mfma<64, false><<<(n + 63) / 64, 256, 0, stream>>>(
      hb, W2, (unsigned short*)hwb, n);
  k_agg64R<<<nbA, 256, 0, stream>>>(desc, rp2, dinv, b2, hwb, out, n);
}

// Round 13
// 223.230 us; speedup vs baseline: 1.5141x; 1.5141x over previous
//
#include <hip/hip_runtime.h>
#include <cstdint>
#include <cstddef>

// GCN on MI355X, round 11 kernel (3rd submit; two infra timeouts, never ran):
// round-6 structure (best measured: 231us) + (a) k_wstart folded into k_fill,
// (b) 8-deep gather ILP in agg128.
//   out[50000,64] = log_softmax(gcn2(relu(gcn1(x))))
// Pipeline: memset -> hist(+rank) -> bsum -> bscan -> scan2(+pad+dinv) ->
//   fill(+wstart) -> MFMA-GEMM1 -> agg128 -> MFMA-GEMM2 -> agg64+logsoftmax
// CSR rows padded to multiples of 4; desc = (bf16 nrm << 16) | src.

#define N_FEAT 128
#define NWAVE 8192   // 2048 blocks x 4 waves = full residency

typedef short bf16x8 __attribute__((ext_vector_type(8)));
typedef float f32x4 __attribute__((ext_vector_type(4)));

__device__ __forceinline__ unsigned f2bf(float f) {
  unsigned u = __float_as_uint(f);
  return (u + 0x7FFFu + ((u >> 16) & 1u)) >> 16;   // round-to-nearest-even
}
__device__ __forceinline__ float bflo(unsigned u) { return __uint_as_float(u << 16); }
__device__ __forceinline__ float bfhi(unsigned u) { return __uint_as_float(u & 0xFFFF0000u); }

// ---------------- preprocessing ----------------

__global__ void k_hist(const int* __restrict__ dst, int* __restrict__ cnt,
                       int* __restrict__ rank, int E) {
  int e = blockIdx.x * blockDim.x + threadIdx.x;
  if (e < E) rank[e] = atomicAdd(&cnt[dst[e]], 1);
}

// Per-block sums of PADDED counts (pad each row to multiple of 4).
__global__ __launch_bounds__(256) void k_bsum(const int* __restrict__ cnt,
                                              int* __restrict__ bsum, int n) {
  int i = blockIdx.x * 256 + threadIdx.x;
  int v = (i < n) ? ((cnt[i] + 3) & ~3) : 0;
  for (int o = 32; o > 0; o >>= 1) v += __shfl_down(v, o);
  __shared__ int w[4];
  if ((threadIdx.x & 63) == 0) w[threadIdx.x >> 6] = v;
  __syncthreads();
  if (threadIdx.x == 0) bsum[blockIdx.x] = w[0] + w[1] + w[2] + w[3];
}

__global__ __launch_bounds__(256) void k_bscan(const int* __restrict__ bsum,
                                               int* __restrict__ bbase, int nb) {
  __shared__ int lds[256];
  int t = threadIdx.x;
  int v = (t < nb) ? bsum[t] : 0;
  lds[t] = v;
  __syncthreads();
  for (int o = 1; o < 256; o <<= 1) {
    int u = (t >= o) ? lds[t - o] : 0;
    __syncthreads();
    lds[t] += u;
    __syncthreads();
  }
  if (t < nb) bbase[t] = lds[t] - v;   // exclusive
}

// Local scan -> rowptr (padded), dinv, and zero the pad descriptor slots.
__global__ __launch_bounds__(256) void k_scan2(const int* __restrict__ cnt,
                                               const int* __restrict__ bbase,
                                               int* __restrict__ rowptr,
                                               float* __restrict__ dinv,
                                               unsigned* __restrict__ desc, int n) {
  __shared__ int lds[256];
  int t = threadIdx.x;
  int i = blockIdx.x * 256 + t;
  int c  = (i < n) ? cnt[i] : 0;
  int pc = (c + 3) & ~3;
  lds[t] = pc;
  __syncthreads();
  for (int o = 1; o < 256; o <<= 1) {
    int u = (t >= o) ? lds[t - o] : 0;
    __syncthreads();
    lds[t] += u;
    __syncthreads();
  }
  if (i < n) {
    int excl = bbase[blockIdx.x] + lds[t] - pc;
    rowptr[i] = excl;
    dinv[i] = rsqrtf((float)(c + 1));          // +1 self-loop
    for (int p = excl + c; p < excl + pc; ++p) desc[p] = 0;  // dummy edges
    if (i == n - 1) rowptr[n] = excl + pc;
  }
}

// CSR fill (atomic-free via ranks) + wave-partition binary search (merged).
__global__ void k_fill(const int* __restrict__ src, const int* __restrict__ dst,
                       const int* __restrict__ rank, const int* __restrict__ rowptr,
                       const float* __restrict__ dinv,
                       unsigned* __restrict__ desc, int* __restrict__ wstart,
                       int E, int n) {
  int gtid = blockIdx.x * blockDim.x + threadIdx.x;
  if (gtid <= NWAVE) {                  // wave partition (rowptr complete here)
    if (gtid == NWAVE) {
      wstart[NWAVE] = n;
    } else {
      int target = (int)((long long)rowptr[n] * gtid / NWAVE);
      int lo = 0, hi = n;
      while (lo < hi) {
        int mid = (lo + hi) >> 1;
        if (rowptr[mid] < target) lo = mid + 1; else hi = mid;
      }
      wstart[gtid] = lo;
    }
  }
  if (gtid >= E) return;
  int s = src[gtid], d = dst[gtid];
  int p = rowptr[d] + rank[gtid];
  desc[p] = (f2bf(dinv[s] * dinv[d]) << 16) | (unsigned)s;
}

// ---------------- MFMA GEMMs (round-6, unchanged) ----------------

template<int NCOL, bool XF32>
__global__ __launch_bounds__(256) void k_gemm_mfma(const void* __restrict__ Xv,
                                                   const float* __restrict__ W,
                                                   unsigned short* __restrict__ Yb,
                                                   int n) {
  constexpr int NT = NCOL / 16;
  __shared__ uint4 Xl[64][16];
  __shared__ uint4 Wl[NCOL][16];
  int t = threadIdx.x;
  int row0 = blockIdx.x * 64;

  for (int c = t; c < 1024; c += 256) {
    int lr = c >> 4, kc = c & 15;
    int row = row0 + lr;
    uint4 v = {0u, 0u, 0u, 0u};
    if (row < n) {
      if constexpr (XF32) {
        const float* Xf = (const float*)Xv;
        float4 f0 = *(const float4*)(Xf + (size_t)row * 128 + kc * 8);
        float4 f1 = *(const float4*)(Xf + (size_t)row * 128 + kc * 8 + 4);
        v.x = f2bf(f0.x) | (f2bf(f0.y) << 16);
        v.y = f2bf(f0.z) | (f2bf(f0.w) << 16);
        v.z = f2bf(f1.x) | (f2bf(f1.y) << 16);
        v.w = f2bf(f1.z) | (f2bf(f1.w) << 16);
      } else {
        v = ((const uint4*)Xv)[(size_t)row * 16 + kc];
      }
    }
    Xl[lr][kc ^ (lr & 7)] = v;
  }
  {
    int j = t % NCOL, kc0 = t / NCOL;
    for (int kc = kc0; kc < 16; kc += 256 / NCOL) {
      const float* wp = W + (size_t)(kc * 8) * NCOL + j;
      float f[8];
#pragma unroll
      for (int e = 0; e < 8; ++e) f[e] = wp[e * NCOL];
      uint4 v;
      v.x = f2bf(f[0]) | (f2bf(f[1]) << 16);
      v.y = f2bf(f[2]) | (f2bf(f[3]) << 16);
      v.z = f2bf(f[4]) | (f2bf(f[5]) << 16);
      v.w = f2bf(f[6]) | (f2bf(f[7]) << 16);
      Wl[j][kc ^ (j & 7)] = v;
    }
  }
  __syncthreads();

  int w = t >> 6, lane = t & 63;
  int lr16 = lane & 15, kg = lane >> 4;
  bf16x8 a[4];
#pragma unroll
  for (int kk = 0; kk < 4; ++kk)
    a[kk] = __builtin_bit_cast(bf16x8, Xl[w * 16 + lr16][(kk * 4 + kg) ^ (lane & 7)]);
#pragma unroll
  for (int jt = 0; jt < NT; ++jt) {
    f32x4 acc = {0.0f, 0.0f, 0.0f, 0.0f};
#pragma unroll
    for (int kk = 0; kk < 4; ++kk) {
      bf16x8 bb = __builtin_bit_cast(bf16x8, Wl[jt * 16 + lr16][(kk * 4 + kg) ^ (lane & 7)]);
      acc = __builtin_amdgcn_mfma_f32_16x16x32_bf16(a[kk], bb, acc, 0, 0, 0);
    }
    int col = jt * 16 + lr16;
#pragma unroll
    for (int r = 0; r < 4; ++r) {
      int row = row0 + w * 16 + kg * 4 + r;
      if (row < n) Yb[(size_t)row * NCOL + col] = (unsigned short)f2bf(acc[r]);
    }
  }
}

// ---------------- aggregations ----------------

// Layer-1: each wave owns rows [wstart[w], wstart[w+1]); lane owns cols
// {2l,2l+1}. 8 edges (8 gathers) in flight per iteration; 4-edge tail.
__global__ __launch_bounds__(256) void k_agg128(const unsigned* __restrict__ desc,
                                                const int* __restrict__ rowptr,
                                                const int* __restrict__ wstart,
                                                const float* __restrict__ dinv,
                                                const float* __restrict__ bias,
                                                const unsigned* __restrict__ xwb,
                                                unsigned* __restrict__ hb, int n) {
  int w    = (blockIdx.x * blockDim.x + threadIdx.x) >> 6;
  int lane = threadIdx.x & 63;
  if (w >= NWAVE) return;
  int r0 = wstart[w], r1 = wstart[w + 1];
  if (r0 >= r1) return;
  float bx0 = bias[2 * lane], bx1 = bias[2 * lane + 1];
  int beg = rowptr[r0];
  for (int r = r0; r < r1; ++r) {
    int end = rowptr[r + 1];
    float di = dinv[r];
    float sl = di * di;
    unsigned us = xwb[(size_t)r * 64 + lane];
    float ax = bx0 + bflo(us) * sl;
    float ay = bx1 + bfhi(us) * sl;
    float bx = 0.0f, by = 0.0f;
    float cx = 0.0f, cy = 0.0f;
    float dx = 0.0f, dy = 0.0f;
    int base = beg;
    for (; base + 8 <= end; base += 8) {     // 8 gathers in flight
      uint4 d4 = *(const uint4*)(desc + base);
      uint4 d5 = *(const uint4*)(desc + base + 4);
      unsigned u0 = xwb[(size_t)(d4.x & 0xFFFFu) * 64 + lane];
      unsigned u1 = xwb[(size_t)(d4.y & 0xFFFFu) * 64 + lane];
      unsigned u2 = xwb[(size_t)(d4.z & 0xFFFFu) * 64 + lane];
      unsigned u3 = xwb[(size_t)(d4.w & 0xFFFFu) * 64 + lane];
      unsigned u4 = xwb[(size_t)(d5.x & 0xFFFFu) * 64 + lane];
      unsigned u5 = xwb[(size_t)(d5.y & 0xFFFFu) * 64 + lane];
      unsigned u6 = xwb[(size_t)(d5.z & 0xFFFFu) * 64 + lane];
      unsigned u7 = xwb[(size_t)(d5.w & 0xFFFFu) * 64 + lane];
      float n0 = bfhi(d4.x), n1 = bfhi(d4.y), n2 = bfhi(d4.z), n3 = bfhi(d4.w);
      float n4 = bfhi(d5.x), n5 = bfhi(d5.y), n6 = bfhi(d5.z), n7 = bfhi(d5.w);
      ax += bflo(u0) * n0; ay += bfhi(u0) * n0;
      bx += bflo(u1) * n1; by += bfhi(u1) * n1;
      cx += bflo(u2) * n2; cy += bfhi(u2) * n2;
      dx += bflo(u3) * n3; dy += bfhi(u3) * n3;
      ax += bflo(u4) * n4; ay += bfhi(u4) * n4;
      bx += bflo(u5) * n5; by += bfhi(u5) * n5;
      cx += bflo(u6) * n6; cy += bfhi(u6) * n6;
      dx += bflo(u7) * n7; dy += bfhi(u7) * n7;
    }
    if (base < end) {                        // padded tail: one 4-group
      uint4 d4 = *(const uint4*)(desc + base);
      unsigned u0 = xwb[(size_t)(d4.x & 0xFFFFu) * 64 + lane];
      unsigned u1 = xwb[(size_t)(d4.y & 0xFFFFu) * 64 + lane];
      unsigned u2 = xwb[(size_t)(d4.z & 0xFFFFu) * 64 + lane];
      unsigned u3 = xwb[(size_t)(d4.w & 0xFFFFu) * 64 + lane];
      float n0 = bfhi(d4.x), n1 = bfhi(d4.y), n2 = bfhi(d4.z), n3 = bfhi(d4.w);
      ax += bflo(u0) * n0; ay += bfhi(u0) * n0;
      bx += bflo(u1) * n1; by += bfhi(u1) * n1;
      cx += bflo(u2) * n2; cy += bfhi(u2) * n2;
      dx += bflo(u3) * n3; dy += bfhi(u3) * n3;
    }
    float ox = fmaxf(ax + bx + cx + dx, 0.0f);
    float oy = fmaxf(ay + by + cy + dy, 0.0f);
    hb[(size_t)r * 64 + lane] = f2bf(ox) | (f2bf(oy) << 16);
    beg = end;
  }
}

// Layer-2 aggregation + log_softmax (round-6 form): half-wave per edge-pair;
// lane owns cols {2c,2c+1} (c=lane&31) of the bf16 table.
__global__ __launch_bounds__(256) void k_agg64ls(const unsigned* __restrict__ desc,
                                                 const int* __restrict__ rowptr,
                                                 const int* __restrict__ wstart,
                                                 const float* __restrict__ dinv,
                                                 const float* __restrict__ bias,
                                                 const unsigned* __restrict__ hwb,
                                                 float* __restrict__ out, int n) {
  int w    = (blockIdx.x * blockDim.x + threadIdx.x) >> 6;
  int lane = threadIdx.x & 63;
  if (w >= NWAVE) return;
  int r0 = wstart[w], r1 = wstart[w + 1];
  if (r0 >= r1) return;
  int c    = lane & 31;
  int half = lane >> 5;
  float bc0 = bias[2 * c], bc1 = bias[2 * c + 1];
  int beg = rowptr[r0];
  for (int r = r0; r < r1; ++r) {
    int end = rowptr[r + 1];
    float ax = 0.0f, ay = 0.0f, bx = 0.0f, by = 0.0f;
    if (half == 0) {   // self-loop + bias counted once
      float di = dinv[r];
      unsigned us = hwb[(size_t)r * 32 + c];
      ax = bc0 + bflo(us) * di * di;
      ay = bc1 + bfhi(us) * di * di;
    }
    for (int base = beg; base < end; base += 4) {
      uint4 d4 = *(const uint4*)(desc + base);
      unsigned dA = half ? d4.z : d4.x;
      unsigned dB = half ? d4.w : d4.y;
      unsigned uA = hwb[(size_t)(dA & 0xFFFFu) * 32 + c];
      unsigned uB = hwb[(size_t)(dB & 0xFFFFu) * 32 + c];
      float nA = bfhi(dA), nB = bfhi(dB);
      ax += bflo(uA) * nA; ay += bfhi(uA) * nA;
      bx += bflo(uB) * nB; by += bfhi(uB) * nB;
    }
    float vx = ax + bx, vy = ay + by;
    vx += __shfl_xor(vx, 32);
    vy += __shfl_xor(vy, 32);
    float m = fmaxf(vx, vy);
    for (int o = 16; o > 0; o >>= 1) m = fmaxf(m, __shfl_xor(m, o));
    float s = expf(vx - m) + expf(vy - m);
    for (int o = 16; o > 0; o >>= 1) s += __shfl_xor(s, o);
    float ls = logf(s);
    if (half == 0) {
      float2 o2 = { vx - m - ls, vy - m - ls };
      *(float2*)(out + (size_t)r * 64 + 2 * c) = o2;
    }
    beg = end;
  }
}

extern "C" void kernel_launch(void* const* d_in, const int* in_sizes, int n_in,
                              void* d_out, int out_size, void* d_ws, size_t ws_size,
                              hipStream_t stream) {
  const float* x  = (const float*)d_in[0];
  const int*   ei = (const int*)d_in[1];
  const float* W1 = (const float*)d_in[2];
  const float* b1 = (const float*)d_in[3];
  const float* W2 = (const float*)d_in[4];
  const float* b2 = (const float*)d_in[5];
  float* out = (float*)d_out;

  const int n = in_sizes[0] / N_FEAT;   // 50000
  const int E = in_sizes[1] / 2;        // 800000
  const int* src = ei;
  const int* dst = ei + E;
  const int nb = (n + 255) / 256;       // 196

  auto align = [](size_t v) { return (v + 255) & ~(size_t)255; };
  char* ws = (char*)d_ws;
  size_t off = 0;
  int*      cnt    = (int*)     (ws + off); off += align((size_t)n * 4);
  int*      rowptr = (int*)     (ws + off); off += align((size_t)(n + 1) * 4);
  float*    dinv   = (float*)   (ws + off); off += align((size_t)n * 4);
  int*      rank   = (int*)     (ws + off); off += align((size_t)E * 4);
  int*      bsum   = (int*)     (ws + off); off += align(256 * 4);
  int*      bbase  = (int*)     (ws + off); off += align(256 * 4);
  int*      wstart = (int*)     (ws + off); off += align((size_t)(NWAVE + 1) * 4);
  unsigned* desc   = (unsigned*)(ws + off); off += align((size_t)(E + 4 * n) * 4);
  unsigned* xwb    = (unsigned*)(ws + off); off += align((size_t)n * 64 * 4);  // bf16[n,128]
  unsigned* hb     = (unsigned*)(ws + off); off += align((size_t)n * 64 * 4);  // bf16[n,128]
  unsigned* hwb    = xwb;  // bf16[n,64] overlays xwb (dead after agg128)

  hipMemsetAsync(cnt, 0, (size_t)n * 4, stream);
  k_hist<<<(E + 255) / 256, 256, 0, stream>>>(dst, cnt, rank, E);
  k_bsum<<<nb, 256, 0, stream>>>(cnt, bsum, n);
  k_bscan<<<1, 256, 0, stream>>>(bsum, bbase, nb);
  k_scan2<<<nb, 256, 0, stream>>>(cnt, bbase, rowptr, dinv, desc, n);
  k_fill<<<(E + 255) / 256, 256, 0, stream>>>(src, dst, rank, rowptr, dinv,
                                              desc, wstart, E, n);

  // Layer 1
  k_gemm_mfma<128, true><<<(n + 63) / 64, 256, 0, stream>>>(
      x, W1, (unsigned short*)xwb, n);
  k_agg128<<<NWAVE / 4, 256, 0, stream>>>(desc, rowptr, wstart, dinv, b1, xwb, hb, n);

  // Layer 2
  k_gemm_mfma<64, false><<<(n + 63) / 64, 256, 0, stream>>>(
      hb, W2, (unsigned short*)hwb, n);
  k_agg64ls<<<NWAVE / 4, 256, 0, stream>>>(desc, rowptr, wstart, dinv, b2, hwb, out, n);
}